// Round 8
// baseline (3287.955 us; speedup 1.0000x reference)
//
#include <hip/hip_runtime.h>

// 4D conv net, MI355X. S=30, B=2, ch 1->10->10->1, kernel 3^4, pad 1, ReLU.
// out = net(x,w) + net(x,w_swap), w_swap has (k1,k2)<->(k3,k4).
// R7: all layers as 32x32x16 bf16 MFMA, M = 32 padded t-positions (full row),
// K = 16 channels, N = k4*10+co. One b128 A-read per h2-row (k3-chained).
// Cross-k4 combine once in epilogue via per-wave LDS transpose.
// R8: XCD-compact block swizzle (XCD = L&7 owns a (z, h-half) slab, sweeping
// w1 fastest -> ~3 MB L2 working set) + occupancy 3 -> 6 blocks/CU.

static constexpr int S  = 30;
static constexpr long S4 = 810000;
static constexpr size_t PLANE = 32768;                  // 32*32*16*2 B
static constexpr size_t YBYTES = (size_t)1800 * PLANE;  // [b(2)][g1][g2]

typedef __bf16 bf16x8 __attribute__((ext_vector_type(8)));
typedef float  f32x16 __attribute__((ext_vector_type(16)));
typedef unsigned int  u32;
typedef unsigned short u16;

static __device__ __forceinline__ u16 f2bf(float f) {
    u32 u = __builtin_bit_cast(u32, f);
    return (u16)((u + 0x7fffu + ((u >> 16) & 1u)) >> 16);
}

// ---------------------------------------------------------------------------
// B-fragment table: [set(6)][k12(9)][k3(3)][lane(64)] uint4.
// set = layer*2 + branch. Layer 0: w1 (K slot 0 only); 1: w2 (K = c, 10/16);
// 2: w3 (K = c, cols {0,10,20} only). N: n = k4*10 + co (n<30).
// B[k][n]: lane = n + 32*hl holds k = hl*8 + j.
__global__ __launch_bounds__(256) void fragprep_k(u32* __restrict__ ft,
    const float* __restrict__ w1, const float* __restrict__ w2,
    const float* __restrict__ w3)
{
    const int gid = blockIdx.x * 256 + threadIdx.x;
    if (gid >= 6 * 27 * 64) return;
    const int lane = gid & 63;
    int r = gid >> 6;
    const int k3 = r % 3; r /= 3;
    const int k12 = r % 9; const int set = r / 9;
    const int layer = set >> 1, swap = set & 1;
    const int k1 = k12 / 3, k2 = k12 % 3;
    const int n = lane & 31, hl = lane >> 5;

    u16 us[8];
#pragma unroll
    for (int j = 0; j < 8; ++j) us[j] = 0;
    if (n < 30) {
        const int k4 = (n < 10) ? 0 : ((n < 20) ? 1 : 2);
        const int co = n - 10 * k4;
        const int i1 = swap ? k3 : k1, i2 = swap ? k4 : k2;
        const int i3 = swap ? k1 : k3, i4 = swap ? k2 : k4;
        const int widx = ((i1 * 3 + i2) * 3 + i3) * 3 + i4;
#pragma unroll
        for (int j = 0; j < 8; ++j) {
            const int k = hl * 8 + j;
            float wv = 0.f;
            if (layer == 0) { if (k == 0) wv = w1[co * 81 + widx]; }
            else if (layer == 1) { if (k < 10) wv = w2[(co * 10 + k) * 81 + widx]; }
            else { if (k < 10 && co == 0) wv = w3[k * 81 + widx]; }
            us[j] = f2bf(wv);
        }
    }
    u32* o = ft + (size_t)gid * 4;
    o[0] = (u32)us[0] | ((u32)us[1] << 16);
    o[1] = (u32)us[2] | ((u32)us[3] << 16);
    o[2] = (u32)us[4] | ((u32)us[5] << 16);
    o[3] = (u32)us[6] | ((u32)us[7] << 16);
}

// ---------------------------------------------------------------------------
// Zero halo positions (h' or t' in {0,31}) of all 1800 planes of y1 and y2.
// Interior c10..15 never needs zeroing: B-table has zero weights for k>=10.
__global__ __launch_bounds__(128) void zerok(u16* __restrict__ y1, u16* __restrict__ y2)
{
    const int pb = blockIdx.x, tid = threadIdx.x;
    if (tid >= 124) return;
    int hp, tp;
    if (tid < 32)      { hp = 0;        tp = tid; }
    else if (tid < 64) { hp = 31;       tp = tid - 32; }
    else if (tid < 94) { hp = tid - 63; tp = 0; }
    else               { hp = tid - 93; tp = 31; }
    const size_t off = (size_t)pb * PLANE + hp * 1024 + tp * 32;
    const uint4 z = make_uint4(0, 0, 0, 0);
    *(uint4*)((char*)y1 + off)      = z;
    *(uint4*)((char*)y1 + off + 16) = z;
    *(uint4*)((char*)y2 + off)      = z;
    *(uint4*)((char*)y2 + off + 16) = z;
}

// ---------------------------------------------------------------------------
// Unified conv layer. Swizzled block = (w1, h1, z), z = b*2 + half; block
// computes h2 rows [half*15, half*15+15). Wave wv owns 4 rows (wave 3: 3).
// LAYER 0: in = x fp32 (bf16-cast in register, K slot 0).
// LAYER 1: in = y1 padded planes, out = y2 padded planes.
// LAYER 2: in = y2, out = fp32 d_out (ACCUM adds for branch 1).
template<int LAYER, bool ACCUM>
__global__ __launch_bounds__(256, 6) void conv_k(
    const void* __restrict__ inp, const u32* __restrict__ ftab,
    const float* __restrict__ bias, void* __restrict__ outp)
{
    __shared__ float E[4][1056];          // per-wave 32 cols x 33-stride rows
    // XCD-compact swizzle: XCD (L&7) sweeps a (z, h-half) slab, w1 fastest.
    const int L = blockIdx.x + 30 * blockIdx.y + 900 * blockIdx.z;
    const int xcd = L & 7, i5 = L >> 3;          // i5 in 0..449
    const int z = xcd >> 1, hh = xcd & 1;
    const int h1 = hh * 15 + i5 / 30;
    const int w1i = i5 % 30;
    const int b = z >> 1, half = z & 1;

    const int tid = threadIdx.x;
    const int lane = tid & 63, wv = tid >> 6;
    const int m = lane & 31, hl = lane >> 5;    // A: row m = padded t', k-group hl
    const int rbase = half * 15 + wv * 4;
    const int rcnt = (wv == 3) ? 3 : 4;

    f32x16 acc[4];
#pragma unroll
    for (int r = 0; r < 4; ++r)
#pragma unroll
        for (int e = 0; e < 16; ++e) acc[r][e] = 0.f;

    int kl[9], nk = 0;
    for (int k12 = 0; k12 < 9; ++k12) {
        const int g1 = h1 + k12 / 3 - 1, g2 = w1i + k12 % 3 - 1;
        if (g1 >= 0 && g1 < S && g2 >= 0 && g2 < S)
            kl[nk++] = (g1 * S + g2) | (k12 << 10);
    }

    const uint4* ft4 = (const uint4*)ftab;
    uint4 B[3];
    {
        const int k0 = kl[0] >> 10;
#pragma unroll
        for (int f = 0; f < 3; ++f) B[f] = ft4[(k0 * 3 + f) * 64 + lane];
    }

    for (int ki = 0; ki < nk; ++ki) {
        const int g = kl[ki] & 1023;
        uint4 F[6];
        if (LAYER == 0) {
            const float* xp = (const float*)inp + ((size_t)b * 900 + g) * 900;
#pragma unroll
            for (int f = 0; f < 6; ++f) {
                if (f > rcnt + 1) continue;
                const int hp = rbase + f;            // h' = h2 + k3
                float v = 0.f;
                if (hl == 0 && hp >= 1 && hp <= 30 && m >= 1 && m <= 30)
                    v = xp[(hp - 1) * 30 + (m - 1)];
                F[f] = make_uint4((u32)f2bf(v), 0u, 0u, 0u);
            }
        } else {
            const char* P = (const char*)inp + ((size_t)b * 900 + g) * PLANE
                            + m * 32 + hl * 16;
#pragma unroll
            for (int f = 0; f < 6; ++f) {
                if (f > rcnt + 1) continue;
                F[f] = *(const uint4*)(P + (size_t)(rbase + f) * 1024);
            }
        }
        uint4 Bn[3];
        {
            const int kn = kl[(ki + 1 < nk) ? ki + 1 : ki] >> 10;
#pragma unroll
            for (int f = 0; f < 3; ++f) Bn[f] = ft4[(kn * 3 + f) * 64 + lane];
        }
#pragma unroll
        for (int r = 0; r < 4; ++r) {
            if (r >= rcnt) continue;                 // wave-uniform
            acc[r] = __builtin_amdgcn_mfma_f32_32x32x16_bf16(
                __builtin_bit_cast(bf16x8, F[r]),     __builtin_bit_cast(bf16x8, B[0]), acc[r], 0, 0, 0);
            acc[r] = __builtin_amdgcn_mfma_f32_32x32x16_bf16(
                __builtin_bit_cast(bf16x8, F[r + 1]), __builtin_bit_cast(bf16x8, B[1]), acc[r], 0, 0, 0);
            acc[r] = __builtin_amdgcn_mfma_f32_32x32x16_bf16(
                __builtin_bit_cast(bf16x8, F[r + 2]), __builtin_bit_cast(bf16x8, B[2]), acc[r], 0, 0, 0);
        }
        B[0] = Bn[0]; B[1] = Bn[1]; B[2] = Bn[2];
    }

    // Epilogue: per tile, transpose P through per-wave LDS, combine k4 shifts:
    // out[t][co] = sum_k4 P[t+k4][k4*10+co]. C/D: col = lane&31,
    // row = (reg&3) + 8*(reg>>2) + 4*hl.
    float* Ew = E[wv];
    for (int r = 0; r < 4; ++r) {
        const bool act = (r < rcnt);
        if (act) {
#pragma unroll
            for (int gq = 0; gq < 4; ++gq)
#pragma unroll
                for (int r4 = 0; r4 < 4; ++r4)
                    Ew[m * 33 + 4 * hl + 8 * gq + r4] = acc[r][gq * 4 + r4];
        }
        __syncthreads();
        if (act) {
            const int h2 = rbase + r;
            if (LAYER <= 1) {
                char* pl = (char*)outp + ((size_t)b * 900 + h1 * S + w1i) * PLANE
                           + (size_t)(h2 + 1) * 1024;
#pragma unroll
                for (int s = 0; s < 3; ++s) {
                    const int o = lane + 64 * s;
                    if (o >= 150) continue;
                    const int t = o / 5, cp = o - 5 * t;
                    const int c0 = 2 * cp, c1 = 2 * cp + 1;
                    float v0 = Ew[c0 * 33 + t] + Ew[(10 + c0) * 33 + t + 1]
                             + Ew[(20 + c0) * 33 + t + 2] + bias[c0];
                    float v1 = Ew[c1 * 33 + t] + Ew[(10 + c1) * 33 + t + 1]
                             + Ew[(20 + c1) * 33 + t + 2] + bias[c1];
                    v0 = fmaxf(v0, 0.f); v1 = fmaxf(v1, 0.f);
                    *(u32*)(pl + (t + 1) * 32 + cp * 4) =
                        (u32)f2bf(v0) | ((u32)f2bf(v1) << 16);
                }
            } else {
                if (lane < 30) {
                    const int t = lane;
                    float v = Ew[t] + Ew[330 + t + 1] + Ew[660 + t + 2] + bias[0];
                    v = fmaxf(v, 0.f);
                    float* o = (float*)outp + (size_t)b * S4
                               + (size_t)(h1 * S + w1i) * 900 + h2 * 30 + t;
                    if (ACCUM) *o += v; else *o = v;
                }
            }
        }
        __syncthreads();
    }
}

// ---------------------------------------------------------------------------
extern "C" void kernel_launch(void* const* d_in, const int* in_sizes, int n_in,
                              void* d_out, int out_size, void* d_ws, size_t ws_size,
                              hipStream_t stream)
{
    const float* x   = (const float*)d_in[0];
    const float* w1p = (const float*)d_in[1];
    const float* b1p = (const float*)d_in[2];
    const float* w2p = (const float*)d_in[3];
    const float* b2p = (const float*)d_in[4];
    const float* w3p = (const float*)d_in[5];
    const float* b3p = (const float*)d_in[6];
    float* out = (float*)d_out;

    // ws: fragtab 6*27*64 uint4 = 165888 B | y1 59 MB | y2 59 MB
    u32* ft = (u32*)d_ws;
    u16* y1 = (u16*)((char*)d_ws + 165888);
    u16* y2 = (u16*)((char*)y1 + YBYTES);

    fragprep_k<<<41, 256, 0, stream>>>(ft, w1p, w2p, w3p);
    zerok<<<1800, 128, 0, stream>>>(y1, y2);

    dim3 grid(S, S, 4), blk(256);
    for (int br = 0; br < 2; ++br) {
        const u32* f1 = ft + (size_t)(0 + br) * 27 * 64 * 4;
        const u32* f2 = ft + (size_t)(2 + br) * 27 * 64 * 4;
        const u32* f3 = ft + (size_t)(4 + br) * 27 * 64 * 4;
        conv_k<0, false><<<grid, blk, 0, stream>>>(x,  f1, b1p, (void*)y1);
        conv_k<1, false><<<grid, blk, 0, stream>>>(y1, f2, b2p, (void*)y2);
        if (br == 0)
            conv_k<2, false><<<grid, blk, 0, stream>>>(y2, f3, b3p, (void*)out);
        else
            conv_k<2, true><<<grid, blk, 0, stream>>>(y2, f3, b3p, (void*)out);
    }
}

// Round 9
// 603.441 us; speedup vs baseline: 5.4487x; 5.4487x over previous
//
#include <hip/hip_runtime.h>

// 4D conv net, MI355X. S=30, B=2, ch 1->10->10->1, kernel 3^4, pad 1, ReLU.
// out = net(x,w) + net(x,w_swap), w_swap has (k1,k2)<->(k3,k4).
// R7 structure: all layers as 32x32x16 bf16 MFMA, M = 32 padded t-positions,
// K = 16 channels, N = k4*10+co. One b128 A-read per h2-row (k3-chained).
// Cross-k4 combine once in epilogue via per-wave LDS transpose.
// R9: natural block order (R8's z-interleaving swizzle thrashed L2 9.4x --
// reverted); epilogue writes FULL 32-B position slots (zeros in c10..15) to
// avoid L2 write-allocate RMW fetch of partial lines; occupancy 3 -> 4.

static constexpr int S  = 30;
static constexpr long S4 = 810000;
static constexpr size_t PLANE = 32768;                  // 32*32*16*2 B
static constexpr size_t YBYTES = (size_t)1800 * PLANE;  // [b(2)][g1][g2]

typedef __bf16 bf16x8 __attribute__((ext_vector_type(8)));
typedef float  f32x16 __attribute__((ext_vector_type(16)));
typedef unsigned int  u32;
typedef unsigned short u16;

static __device__ __forceinline__ u16 f2bf(float f) {
    u32 u = __builtin_bit_cast(u32, f);
    return (u16)((u + 0x7fffu + ((u >> 16) & 1u)) >> 16);
}

// ---------------------------------------------------------------------------
// B-fragment table: [set(6)][k12(9)][k3(3)][lane(64)] uint4.
// set = layer*2 + branch. Layer 0: w1 (K slot 0 only); 1: w2 (K = c, 10/16);
// 2: w3 (K = c, cols {0,10,20} only). N: n = k4*10 + co (n<30).
// B[k][n]: lane = n + 32*hl holds k = hl*8 + j.
__global__ __launch_bounds__(256) void fragprep_k(u32* __restrict__ ft,
    const float* __restrict__ w1, const float* __restrict__ w2,
    const float* __restrict__ w3)
{
    const int gid = blockIdx.x * 256 + threadIdx.x;
    if (gid >= 6 * 27 * 64) return;
    const int lane = gid & 63;
    int r = gid >> 6;
    const int k3 = r % 3; r /= 3;
    const int k12 = r % 9; const int set = r / 9;
    const int layer = set >> 1, swap = set & 1;
    const int k1 = k12 / 3, k2 = k12 % 3;
    const int n = lane & 31, hl = lane >> 5;

    u16 us[8];
#pragma unroll
    for (int j = 0; j < 8; ++j) us[j] = 0;
    if (n < 30) {
        const int k4 = (n < 10) ? 0 : ((n < 20) ? 1 : 2);
        const int co = n - 10 * k4;
        const int i1 = swap ? k3 : k1, i2 = swap ? k4 : k2;
        const int i3 = swap ? k1 : k3, i4 = swap ? k2 : k4;
        const int widx = ((i1 * 3 + i2) * 3 + i3) * 3 + i4;
#pragma unroll
        for (int j = 0; j < 8; ++j) {
            const int k = hl * 8 + j;
            float wv = 0.f;
            if (layer == 0) { if (k == 0) wv = w1[co * 81 + widx]; }
            else if (layer == 1) { if (k < 10) wv = w2[(co * 10 + k) * 81 + widx]; }
            else { if (k < 10 && co == 0) wv = w3[k * 81 + widx]; }
            us[j] = f2bf(wv);
        }
    }
    u32* o = ft + (size_t)gid * 4;
    o[0] = (u32)us[0] | ((u32)us[1] << 16);
    o[1] = (u32)us[2] | ((u32)us[3] << 16);
    o[2] = (u32)us[4] | ((u32)us[5] << 16);
    o[3] = (u32)us[6] | ((u32)us[7] << 16);
}

// ---------------------------------------------------------------------------
// Zero halo positions (h' or t' in {0,31}) of all 1800 planes of y1 and y2.
__global__ __launch_bounds__(128) void zerok(u16* __restrict__ y1, u16* __restrict__ y2)
{
    const int pb = blockIdx.x, tid = threadIdx.x;
    if (tid >= 124) return;
    int hp, tp;
    if (tid < 32)      { hp = 0;        tp = tid; }
    else if (tid < 64) { hp = 31;       tp = tid - 32; }
    else if (tid < 94) { hp = tid - 63; tp = 0; }
    else               { hp = tid - 93; tp = 31; }
    const size_t off = (size_t)pb * PLANE + hp * 1024 + tp * 32;
    const uint4 z = make_uint4(0, 0, 0, 0);
    *(uint4*)((char*)y1 + off)      = z;
    *(uint4*)((char*)y1 + off + 16) = z;
    *(uint4*)((char*)y2 + off)      = z;
    *(uint4*)((char*)y2 + off + 16) = z;
}

// ---------------------------------------------------------------------------
// Unified conv layer. Block = (w1, h1, z), z = b*2 + half; block computes
// h2 rows [half*15, half*15+15). Wave wv owns 4 rows (wave 3: 3).
// LAYER 0: in = x fp32 (bf16-cast in register, K slot 0).
// LAYER 1: in = y1 padded planes, out = y2 padded planes.
// LAYER 2: in = y2, out = fp32 d_out (ACCUM adds for branch 1).
template<int LAYER, bool ACCUM>
__global__ __launch_bounds__(256, 4) void conv_k(
    const void* __restrict__ inp, const u32* __restrict__ ftab,
    const float* __restrict__ bias, void* __restrict__ outp)
{
    __shared__ float E[4][1056];          // per-wave 32 cols x 33-stride rows
    const int w1i = blockIdx.x, h1 = blockIdx.y;
    const int b = blockIdx.z >> 1, half = blockIdx.z & 1;
    const int tid = threadIdx.x;
    const int lane = tid & 63, wv = tid >> 6;
    const int m = lane & 31, hl = lane >> 5;    // A: row m = padded t', k-group hl
    const int rbase = half * 15 + wv * 4;
    const int rcnt = (wv == 3) ? 3 : 4;

    f32x16 acc[4];
#pragma unroll
    for (int r = 0; r < 4; ++r)
#pragma unroll
        for (int e = 0; e < 16; ++e) acc[r][e] = 0.f;

    int kl[9], nk = 0;
    for (int k12 = 0; k12 < 9; ++k12) {
        const int g1 = h1 + k12 / 3 - 1, g2 = w1i + k12 % 3 - 1;
        if (g1 >= 0 && g1 < S && g2 >= 0 && g2 < S)
            kl[nk++] = (g1 * S + g2) | (k12 << 10);
    }

    const uint4* ft4 = (const uint4*)ftab;
    uint4 B[3];
    {
        const int k0 = kl[0] >> 10;
#pragma unroll
        for (int f = 0; f < 3; ++f) B[f] = ft4[(k0 * 3 + f) * 64 + lane];
    }

    for (int ki = 0; ki < nk; ++ki) {
        const int g = kl[ki] & 1023;
        uint4 F[6];
        if (LAYER == 0) {
            const float* xp = (const float*)inp + ((size_t)b * 900 + g) * 900;
#pragma unroll
            for (int f = 0; f < 6; ++f) {
                if (f > rcnt + 1) continue;
                const int hp = rbase + f;            // h' = h2 + k3
                float v = 0.f;
                if (hl == 0 && hp >= 1 && hp <= 30 && m >= 1 && m <= 30)
                    v = xp[(hp - 1) * 30 + (m - 1)];
                F[f] = make_uint4((u32)f2bf(v), 0u, 0u, 0u);
            }
        } else {
            const char* P = (const char*)inp + ((size_t)b * 900 + g) * PLANE
                            + m * 32 + hl * 16;
#pragma unroll
            for (int f = 0; f < 6; ++f) {
                if (f > rcnt + 1) continue;
                F[f] = *(const uint4*)(P + (size_t)(rbase + f) * 1024);
            }
        }
        uint4 Bn[3];
        {
            const int kn = kl[(ki + 1 < nk) ? ki + 1 : ki] >> 10;
#pragma unroll
            for (int f = 0; f < 3; ++f) Bn[f] = ft4[(kn * 3 + f) * 64 + lane];
        }
#pragma unroll
        for (int r = 0; r < 4; ++r) {
            if (r >= rcnt) continue;                 // wave-uniform
            acc[r] = __builtin_amdgcn_mfma_f32_32x32x16_bf16(
                __builtin_bit_cast(bf16x8, F[r]),     __builtin_bit_cast(bf16x8, B[0]), acc[r], 0, 0, 0);
            acc[r] = __builtin_amdgcn_mfma_f32_32x32x16_bf16(
                __builtin_bit_cast(bf16x8, F[r + 1]), __builtin_bit_cast(bf16x8, B[1]), acc[r], 0, 0, 0);
            acc[r] = __builtin_amdgcn_mfma_f32_32x32x16_bf16(
                __builtin_bit_cast(bf16x8, F[r + 2]), __builtin_bit_cast(bf16x8, B[2]), acc[r], 0, 0, 0);
        }
        B[0] = Bn[0]; B[1] = Bn[1]; B[2] = Bn[2];
    }

    // Epilogue: per tile, transpose P through per-wave LDS, combine k4 shifts:
    // out[t][co] = sum_k4 P[t+k4][k4*10+co]. C/D: col = lane&31,
    // row = (reg&3) + 8*(reg>>2) + 4*hl.
    float* Ew = E[wv];
    for (int r = 0; r < 4; ++r) {
        const bool act = (r < rcnt);
        if (act) {
#pragma unroll
            for (int gq = 0; gq < 4; ++gq)
#pragma unroll
                for (int r4 = 0; r4 < 4; ++r4)
                    Ew[m * 33 + 4 * hl + 8 * gq + r4] = acc[r][gq * 4 + r4];
        }
        __syncthreads();
        if (act) {
            const int h2 = rbase + r;
            if (LAYER <= 1) {
                // Full 32-B slots: cp = 0..7 (cp >= 5 writes zeros) so y-lines
                // are fully dirtied -> no write-allocate RMW fetch.
                char* pl = (char*)outp + ((size_t)b * 900 + h1 * S + w1i) * PLANE
                           + (size_t)(h2 + 1) * 1024;
#pragma unroll
                for (int s = 0; s < 4; ++s) {
                    const int o = lane + 64 * s;
                    if (o >= 240) continue;
                    const int t = o >> 3, cp = o & 7;
                    u32 pk = 0;
                    if (cp < 5) {
                        const int c0 = 2 * cp, c1 = 2 * cp + 1;
                        float v0 = Ew[c0 * 33 + t] + Ew[(10 + c0) * 33 + t + 1]
                                 + Ew[(20 + c0) * 33 + t + 2] + bias[c0];
                        float v1 = Ew[c1 * 33 + t] + Ew[(10 + c1) * 33 + t + 1]
                                 + Ew[(20 + c1) * 33 + t + 2] + bias[c1];
                        v0 = fmaxf(v0, 0.f); v1 = fmaxf(v1, 0.f);
                        pk = (u32)f2bf(v0) | ((u32)f2bf(v1) << 16);
                    }
                    *(u32*)(pl + (t + 1) * 32 + cp * 4) = pk;
                }
            } else {
                if (lane < 30) {
                    const int t = lane;
                    float v = Ew[t] + Ew[330 + t + 1] + Ew[660 + t + 2] + bias[0];
                    v = fmaxf(v, 0.f);
                    float* o = (float*)outp + (size_t)b * S4
                               + (size_t)(h1 * S + w1i) * 900 + h2 * 30 + t;
                    if (ACCUM) *o += v; else *o = v;
                }
            }
        }
        __syncthreads();
    }
}

// ---------------------------------------------------------------------------
extern "C" void kernel_launch(void* const* d_in, const int* in_sizes, int n_in,
                              void* d_out, int out_size, void* d_ws, size_t ws_size,
                              hipStream_t stream)
{
    const float* x   = (const float*)d_in[0];
    const float* w1p = (const float*)d_in[1];
    const float* b1p = (const float*)d_in[2];
    const float* w2p = (const float*)d_in[3];
    const float* b2p = (const float*)d_in[4];
    const float* w3p = (const float*)d_in[5];
    const float* b3p = (const float*)d_in[6];
    float* out = (float*)d_out;

    // ws: fragtab 6*27*64 uint4 = 165888 B | y1 59 MB | y2 59 MB
    u32* ft = (u32*)d_ws;
    u16* y1 = (u16*)((char*)d_ws + 165888);
    u16* y2 = (u16*)((char*)y1 + YBYTES);

    fragprep_k<<<41, 256, 0, stream>>>(ft, w1p, w2p, w3p);
    zerok<<<1800, 128, 0, stream>>>(y1, y2);

    dim3 grid(S, S, 4), blk(256);
    for (int br = 0; br < 2; ++br) {
        const u32* f1 = ft + (size_t)(0 + br) * 27 * 64 * 4;
        const u32* f2 = ft + (size_t)(2 + br) * 27 * 64 * 4;
        const u32* f3 = ft + (size_t)(4 + br) * 27 * 64 * 4;
        conv_k<0, false><<<grid, blk, 0, stream>>>(x,  f1, b1p, (void*)y1);
        conv_k<1, false><<<grid, blk, 0, stream>>>(y1, f2, b2p, (void*)y2);
        if (br == 0)
            conv_k<2, false><<<grid, blk, 0, stream>>>(y2, f3, b3p, (void*)out);
        else
            conv_k<2, true><<<grid, blk, 0, stream>>>(y2, f3, b3p, (void*)out);
    }
}

// Round 10
// 596.889 us; speedup vs baseline: 5.5085x; 1.0110x over previous
//
#include <hip/hip_runtime.h>

// 4D conv net, MI355X. S=30, B=2, ch 1->10->10->1, kernel 3^4, pad 1, ReLU.
// out = net(x,w) + net(x,w_swap), w_swap has (k1,k2)<->(k3,k4).
// R7 structure: all layers as 32x32x16 bf16 MFMA, M = 32 padded t-positions,
// K = 16 channels, N = k4*10+co. One b128 A-read per h2-row (k3-chained).
// Cross-k4 combine once in epilogue via per-wave LDS transpose.
// R10: software-pipelined A-fragment loads -- k12+1's 6 plane loads issue
// before k12's MFMAs (register dbuf), so the pre-MFMA waitcnt targets loads
// a full iteration old. LAYER 0 keeps the unpipelined scalar-x path.

static constexpr int S  = 30;
static constexpr long S4 = 810000;
static constexpr size_t PLANE = 32768;                  // 32*32*16*2 B
static constexpr size_t YBYTES = (size_t)1800 * PLANE;  // [b(2)][g1][g2]

typedef __bf16 bf16x8 __attribute__((ext_vector_type(8)));
typedef float  f32x16 __attribute__((ext_vector_type(16)));
typedef unsigned int  u32;
typedef unsigned short u16;

static __device__ __forceinline__ u16 f2bf(float f) {
    u32 u = __builtin_bit_cast(u32, f);
    return (u16)((u + 0x7fffu + ((u >> 16) & 1u)) >> 16);
}

// ---------------------------------------------------------------------------
// B-fragment table: [set(6)][k12(9)][k3(3)][lane(64)] uint4.
// set = layer*2 + branch. Layer 0: w1 (K slot 0 only); 1: w2 (K = c, 10/16);
// 2: w3 (K = c, cols {0,10,20} only). N: n = k4*10 + co (n<30).
// B[k][n]: lane = n + 32*hl holds k = hl*8 + j.
__global__ __launch_bounds__(256) void fragprep_k(u32* __restrict__ ft,
    const float* __restrict__ w1, const float* __restrict__ w2,
    const float* __restrict__ w3)
{
    const int gid = blockIdx.x * 256 + threadIdx.x;
    if (gid >= 6 * 27 * 64) return;
    const int lane = gid & 63;
    int r = gid >> 6;
    const int k3 = r % 3; r /= 3;
    const int k12 = r % 9; const int set = r / 9;
    const int layer = set >> 1, swap = set & 1;
    const int k1 = k12 / 3, k2 = k12 % 3;
    const int n = lane & 31, hl = lane >> 5;

    u16 us[8];
#pragma unroll
    for (int j = 0; j < 8; ++j) us[j] = 0;
    if (n < 30) {
        const int k4 = (n < 10) ? 0 : ((n < 20) ? 1 : 2);
        const int co = n - 10 * k4;
        const int i1 = swap ? k3 : k1, i2 = swap ? k4 : k2;
        const int i3 = swap ? k1 : k3, i4 = swap ? k2 : k4;
        const int widx = ((i1 * 3 + i2) * 3 + i3) * 3 + i4;
#pragma unroll
        for (int j = 0; j < 8; ++j) {
            const int k = hl * 8 + j;
            float wv = 0.f;
            if (layer == 0) { if (k == 0) wv = w1[co * 81 + widx]; }
            else if (layer == 1) { if (k < 10) wv = w2[(co * 10 + k) * 81 + widx]; }
            else { if (k < 10 && co == 0) wv = w3[k * 81 + widx]; }
            us[j] = f2bf(wv);
        }
    }
    u32* o = ft + (size_t)gid * 4;
    o[0] = (u32)us[0] | ((u32)us[1] << 16);
    o[1] = (u32)us[2] | ((u32)us[3] << 16);
    o[2] = (u32)us[4] | ((u32)us[5] << 16);
    o[3] = (u32)us[6] | ((u32)us[7] << 16);
}

// ---------------------------------------------------------------------------
// Zero halo positions (h' or t' in {0,31}) of all 1800 planes of y1 and y2.
__global__ __launch_bounds__(128) void zerok(u16* __restrict__ y1, u16* __restrict__ y2)
{
    const int pb = blockIdx.x, tid = threadIdx.x;
    if (tid >= 124) return;
    int hp, tp;
    if (tid < 32)      { hp = 0;        tp = tid; }
    else if (tid < 64) { hp = 31;       tp = tid - 32; }
    else if (tid < 94) { hp = tid - 63; tp = 0; }
    else               { hp = tid - 93; tp = 31; }
    const size_t off = (size_t)pb * PLANE + hp * 1024 + tp * 32;
    const uint4 z = make_uint4(0, 0, 0, 0);
    *(uint4*)((char*)y1 + off)      = z;
    *(uint4*)((char*)y1 + off + 16) = z;
    *(uint4*)((char*)y2 + off)      = z;
    *(uint4*)((char*)y2 + off + 16) = z;
}

// ---------------------------------------------------------------------------
// Unified conv layer. Block = (w1, h1, z), z = b*2 + half; block computes
// h2 rows [half*15, half*15+15). Wave wv owns 4 rows (wave 3: 3).
// LAYER 0: in = x fp32 (bf16-cast in register, K slot 0), unpipelined.
// LAYER 1: in = y1 padded planes, out = y2 padded planes.   (pipelined)
// LAYER 2: in = y2, out = fp32 d_out (ACCUM adds, branch 1). (pipelined)
template<int LAYER, bool ACCUM>
__global__ __launch_bounds__(256, 3) void conv_k(
    const void* __restrict__ inp, const u32* __restrict__ ftab,
    const float* __restrict__ bias, void* __restrict__ outp)
{
    __shared__ float E[4][1056];          // per-wave 32 cols x 33-stride rows
    const int w1i = blockIdx.x, h1 = blockIdx.y;
    const int b = blockIdx.z >> 1, half = blockIdx.z & 1;
    const int tid = threadIdx.x;
    const int lane = tid & 63, wv = tid >> 6;
    const int m = lane & 31, hl = lane >> 5;    // A: row m = padded t', k-group hl
    const int rbase = half * 15 + wv * 4;
    const int rcnt = (wv == 3) ? 3 : 4;
    const int fmax = rcnt + 1;                  // rows rbase..rbase+fmax used

    f32x16 acc[4];
#pragma unroll
    for (int r = 0; r < 4; ++r)
#pragma unroll
        for (int e = 0; e < 16; ++e) acc[r][e] = 0.f;

    int kl[9], nk = 0;
    for (int k12 = 0; k12 < 9; ++k12) {
        const int g1 = h1 + k12 / 3 - 1, g2 = w1i + k12 % 3 - 1;
        if (g1 >= 0 && g1 < S && g2 >= 0 && g2 < S)
            kl[nk++] = (g1 * S + g2) | (k12 << 10);
    }

    const uint4* ft4 = (const uint4*)ftab;
    const char* Ybase = (const char*)inp + (size_t)b * 900 * PLANE
                        + m * 32 + hl * 16 + (size_t)rbase * 1024;

    uint4 B[3];
    {
        const int k0 = kl[0] >> 10;
#pragma unroll
        for (int f = 0; f < 3; ++f) B[f] = ft4[(k0 * 3 + f) * 64 + lane];
    }

    // A-fragment register double-buffer (LAYER 1/2 only)
    uint4 Fc[6];
    if (LAYER != 0) {
        const char* P = Ybase + (size_t)(kl[0] & 1023) * PLANE;
#pragma unroll
        for (int f = 0; f < 6; ++f)
            if (f <= fmax) Fc[f] = *(const uint4*)(P + (size_t)f * 1024);
    }

    for (int ki = 0; ki < nk; ++ki) {
        // LAYER 0: load current fragments (unpipelined scalar-x path)
        if (LAYER == 0) {
            const int g = kl[ki] & 1023;
            const float* xp = (const float*)inp + ((size_t)b * 900 + g) * 900;
#pragma unroll
            for (int f = 0; f < 6; ++f) {
                if (f > fmax) continue;
                const int hp = rbase + f;            // h' = h2 + k3
                float v = 0.f;
                if (hl == 0 && hp >= 1 && hp <= 30 && m >= 1 && m <= 30)
                    v = xp[(hp - 1) * 30 + (m - 1)];
                Fc[f] = make_uint4((u32)f2bf(v), 0u, 0u, 0u);
            }
        }
        // issue NEXT k12's A loads before this k12's MFMAs (hidden a full iter)
        uint4 Fn[6];
        if (LAYER != 0) {
            const char* Pn = Ybase
                + (size_t)(kl[(ki + 1 < nk) ? ki + 1 : ki] & 1023) * PLANE;
#pragma unroll
            for (int f = 0; f < 6; ++f)
                if (f <= fmax) Fn[f] = *(const uint4*)(Pn + (size_t)f * 1024);
        }
        uint4 Bn[3];
        {
            const int kn = kl[(ki + 1 < nk) ? ki + 1 : ki] >> 10;
#pragma unroll
            for (int f = 0; f < 3; ++f) Bn[f] = ft4[(kn * 3 + f) * 64 + lane];
        }
#pragma unroll
        for (int r = 0; r < 4; ++r) {
            if (r >= rcnt) continue;                 // wave-uniform
            acc[r] = __builtin_amdgcn_mfma_f32_32x32x16_bf16(
                __builtin_bit_cast(bf16x8, Fc[r]),     __builtin_bit_cast(bf16x8, B[0]), acc[r], 0, 0, 0);
            acc[r] = __builtin_amdgcn_mfma_f32_32x32x16_bf16(
                __builtin_bit_cast(bf16x8, Fc[r + 1]), __builtin_bit_cast(bf16x8, B[1]), acc[r], 0, 0, 0);
            acc[r] = __builtin_amdgcn_mfma_f32_32x32x16_bf16(
                __builtin_bit_cast(bf16x8, Fc[r + 2]), __builtin_bit_cast(bf16x8, B[2]), acc[r], 0, 0, 0);
        }
        if (LAYER != 0) {
#pragma unroll
            for (int f = 0; f < 6; ++f) Fc[f] = Fn[f];
        }
        B[0] = Bn[0]; B[1] = Bn[1]; B[2] = Bn[2];
    }

    // Epilogue: per tile, transpose P through per-wave LDS, combine k4 shifts:
    // out[t][co] = sum_k4 P[t+k4][k4*10+co]. C/D: col = lane&31,
    // row = (reg&3) + 8*(reg>>2) + 4*hl.
    float* Ew = E[wv];
    for (int r = 0; r < 4; ++r) {
        const bool act = (r < rcnt);
        if (act) {
#pragma unroll
            for (int gq = 0; gq < 4; ++gq)
#pragma unroll
                for (int r4 = 0; r4 < 4; ++r4)
                    Ew[m * 33 + 4 * hl + 8 * gq + r4] = acc[r][gq * 4 + r4];
        }
        __syncthreads();
        if (act) {
            const int h2 = rbase + r;
            if (LAYER <= 1) {
                // Full 32-B slots (cp >= 5 writes zeros): lines fully dirtied.
                char* pl = (char*)outp + ((size_t)b * 900 + h1 * S + w1i) * PLANE
                           + (size_t)(h2 + 1) * 1024;
#pragma unroll
                for (int s = 0; s < 4; ++s) {
                    const int o = lane + 64 * s;
                    if (o >= 240) continue;
                    const int t = o >> 3, cp = o & 7;
                    u32 pk = 0;
                    if (cp < 5) {
                        const int c0 = 2 * cp, c1 = 2 * cp + 1;
                        float v0 = Ew[c0 * 33 + t] + Ew[(10 + c0) * 33 + t + 1]
                                 + Ew[(20 + c0) * 33 + t + 2] + bias[c0];
                        float v1 = Ew[c1 * 33 + t] + Ew[(10 + c1) * 33 + t + 1]
                                 + Ew[(20 + c1) * 33 + t + 2] + bias[c1];
                        v0 = fmaxf(v0, 0.f); v1 = fmaxf(v1, 0.f);
                        pk = (u32)f2bf(v0) | ((u32)f2bf(v1) << 16);
                    }
                    *(u32*)(pl + (t + 1) * 32 + cp * 4) = pk;
                }
            } else {
                if (lane < 30) {
                    const int t = lane;
                    float v = Ew[t] + Ew[330 + t + 1] + Ew[660 + t + 2] + bias[0];
                    v = fmaxf(v, 0.f);
                    float* o = (float*)outp + (size_t)b * S4
                               + (size_t)(h1 * S + w1i) * 900 + h2 * 30 + t;
                    if (ACCUM) *o += v; else *o = v;
                }
            }
        }
        __syncthreads();
    }
}

// ---------------------------------------------------------------------------
extern "C" void kernel_launch(void* const* d_in, const int* in_sizes, int n_in,
                              void* d_out, int out_size, void* d_ws, size_t ws_size,
                              hipStream_t stream)
{
    const float* x   = (const float*)d_in[0];
    const float* w1p = (const float*)d_in[1];
    const float* b1p = (const float*)d_in[2];
    const float* w2p = (const float*)d_in[3];
    const float* b2p = (const float*)d_in[4];
    const float* w3p = (const float*)d_in[5];
    const float* b3p = (const float*)d_in[6];
    float* out = (float*)d_out;

    // ws: fragtab 6*27*64 uint4 = 165888 B | y1 59 MB | y2 59 MB
    u32* ft = (u32*)d_ws;
    u16* y1 = (u16*)((char*)d_ws + 165888);
    u16* y2 = (u16*)((char*)y1 + YBYTES);

    fragprep_k<<<41, 256, 0, stream>>>(ft, w1p, w2p, w3p);
    zerok<<<1800, 128, 0, stream>>>(y1, y2);

    dim3 grid(S, S, 4), blk(256);
    for (int br = 0; br < 2; ++br) {
        const u32* f1 = ft + (size_t)(0 + br) * 27 * 64 * 4;
        const u32* f2 = ft + (size_t)(2 + br) * 27 * 64 * 4;
        const u32* f3 = ft + (size_t)(4 + br) * 27 * 64 * 4;
        conv_k<0, false><<<grid, blk, 0, stream>>>(x,  f1, b1p, (void*)y1);
        conv_k<1, false><<<grid, blk, 0, stream>>>(y1, f2, b2p, (void*)y2);
        if (br == 0)
            conv_k<2, false><<<grid, blk, 0, stream>>>(y2, f3, b3p, (void*)out);
        else
            conv_k<2, true><<<grid, blk, 0, stream>>>(y2, f3, b3p, (void*)out);
    }
}